// Round 1
// 230.586 us; speedup vs baseline: 1.0717x; 1.0717x over previous
//
#include <hip/hip_runtime.h>
#include <hip/hip_bf16.h>
#include <stdint.h>

typedef unsigned short u16;
typedef unsigned int u32;

typedef __attribute__((ext_vector_type(8))) __bf16 bf16x8;
typedef __attribute__((ext_vector_type(4))) float f32x4;
typedef __attribute__((ext_vector_type(8))) u16 u16x8;

#define DIM 1024
#define SEQ 4096
#define NTOK 8192   // b*n
#define NBH 16      // b*h
#define NSLOT 96    // per-head split-K slots: qt<32 -> 1 chunk, qt>=32 -> 2 chunks (32 k-tiles each)

static __device__ __forceinline__ float bf2f(u16 u) {
    union { u32 u; float f; } c; c.u = ((u32)u) << 16; return c.f;
}
static __device__ __forceinline__ u16 f2bf(float f) {
    union { float f; u32 u; } c; c.f = f;
    u32 u = c.u;
    return (u16)((u + 0x7FFF + ((u >> 16) & 1)) >> 16);
}
static __device__ __forceinline__ u16 cvt_bf16(float f) {
    union { __bf16 b; u16 u; } c; c.b = (__bf16)f;  // RNE
    return c.u;
}
static __device__ __forceinline__ u32 pack_bf16(float lo, float hi) {
    return (u32)cvt_bf16(lo) | ((u32)cvt_bf16(hi) << 16);
}
static __device__ __forceinline__ f32x4 mfma_bf16(bf16x8 a, bf16x8 b, f32x4 c) {
    return __builtin_amdgcn_mfma_f32_16x16x32_bf16(a, b, c, 0, 0, 0);
}

typedef const __attribute__((address_space(1))) unsigned int* gptr_t;
typedef __attribute__((address_space(3))) unsigned int* lptr_t;

// ---------------- LayerNorm: one block per token row (fp32 in, bf16 out) ----
__global__ __launch_bounds__(256) void ln_kernel(const float* __restrict__ x,
                                                 const float* __restrict__ g,
                                                 const float* __restrict__ bta,
                                                 u16* __restrict__ xn) {
    int row = blockIdx.x;
    int tid = threadIdx.x;
    float4 v = ((const float4*)(x + (size_t)row * DIM))[tid];
    float f[4] = {v.x, v.y, v.z, v.w};
    float s = 0.f, s2 = 0.f;
#pragma unroll
    for (int i = 0; i < 4; i++) { s += f[i]; s2 += f[i] * f[i]; }
#pragma unroll
    for (int m = 1; m < 64; m <<= 1) { s += __shfl_xor(s, m); s2 += __shfl_xor(s2, m); }
    __shared__ float red[8];
    int w = tid >> 6;
    if ((tid & 63) == 0) { red[w * 2] = s; red[w * 2 + 1] = s2; }
    __syncthreads();
    s  = red[0] + red[2] + red[4] + red[6];
    s2 = red[1] + red[3] + red[5] + red[7];
    float mu = s * (1.f / DIM);
    float var = s2 * (1.f / DIM) - mu * mu;
    float rstd = rsqrtf(var + 1e-5f);
    u16 o[4];
#pragma unroll
    for (int i = 0; i < 4; i++) {
        int c = tid * 4 + i;
        o[i] = f2bf((f[i] - mu) * rstd * g[c] + bta[c]);
    }
    *(uint64_t*)(xn + (size_t)row * DIM + tid * 4) = *(uint64_t*)o;
}

// ---------------- transpose src[R][C] fp32 -> dst[C][R] bf16 ----------------
__global__ __launch_bounds__(256) void transpose_kernel(const float* __restrict__ src,
                                                        u16* __restrict__ dst,
                                                        int R, int C) {
    __shared__ float t[32][33];
    int lx = threadIdx.x & 31, ly = threadIdx.x >> 5;
    int c = blockIdx.x * 32 + lx;
#pragma unroll
    for (int i = 0; i < 32; i += 8)
        t[ly + i][lx] = src[(size_t)(blockIdx.y * 32 + ly + i) * C + c];
    __syncthreads();
    int rr = blockIdx.y * 32 + lx;
#pragma unroll
    for (int i = 0; i < 32; i += 8)
        dst[(size_t)(blockIdx.x * 32 + ly + i) * R + rr] = f2bf(t[lx][ly + i]);
}

// ---------------- 128x128 MFMA GEMM core (m97-style global_load_lds) -------
template <int K>
static __device__ __forceinline__ void gemm_core(const u16* __restrict__ A,
                                                 const u16* __restrict__ B,
                                                 int rowBase, int colBase,
                                                 u16* A_lds, u16* B_lds,
                                                 f32x4 acc[4][4]) {
    int tid = threadIdx.x;
    int lane = tid & 63;
    int l15 = lane & 15, q4 = lane >> 4;
    int w = tid >> 6;
    int wm = w >> 1, wn = w & 1;
#pragma unroll
    for (int mt = 0; mt < 4; mt++)
#pragma unroll
        for (int nt = 0; nt < 4; nt++) acc[mt][nt] = (f32x4){0.f, 0.f, 0.f, 0.f};

    char* Ab = (char*)A_lds;
    char* Bb = (char*)B_lds;

    for (int k0 = 0; k0 < K; k0 += 32) {
        __syncthreads();
#pragma unroll
        for (int i = 0; i < 2; i++) {
            int c = i * 256 + tid;
            int r = c >> 2;
            int piece = (c & 3) * 8;
            const u16* gA = A + (size_t)(rowBase + r) * K + k0 + piece;
            const u16* gB = B + (size_t)(colBase + r) * K + k0 + piece;
            unsigned ldsOff = (unsigned)(i * 4096 + w * 1024);  // wave-uniform
            __builtin_amdgcn_global_load_lds((gptr_t)gA, (lptr_t)(Ab + ldsOff), 16, 0, 0);
            __builtin_amdgcn_global_load_lds((gptr_t)gB, (lptr_t)(Bb + ldsOff), 16, 0, 0);
        }
        __syncthreads();
        bf16x8 a[4], b[4];
#pragma unroll
        for (int mt = 0; mt < 4; mt++)
            a[mt] = *(const bf16x8*)(A_lds + (wm * 64 + mt * 16 + l15) * 32 + q4 * 8);
#pragma unroll
        for (int nt = 0; nt < 4; nt++)
            b[nt] = *(const bf16x8*)(B_lds + (wn * 64 + nt * 16 + l15) * 32 + q4 * 8);
#pragma unroll
        for (int mt = 0; mt < 4; mt++)
#pragma unroll
            for (int nt = 0; nt < 4; nt++)
                acc[mt][nt] = mfma_bf16(a[mt], b[nt], acc[mt][nt]);
    }
}

// QKV GEMM: q gets softmax scale pre-folded; v stored transposed [bh][d][n]
__global__ __launch_bounds__(256) void gemm_qkv_kernel(const u16* __restrict__ xn,
                                                       const u16* __restrict__ wT,
                                                       u16* __restrict__ qb,
                                                       u16* __restrict__ kb,
                                                       u16* __restrict__ vbT) {
    __shared__ u16 A_lds[128 * 32];
    __shared__ u16 B_lds[128 * 32];
    f32x4 acc[4][4];
    gemm_core<1024>(xn, wT, blockIdx.x * 128, blockIdx.y * 128, A_lds, B_lds, acc);
    int lane = threadIdx.x & 63;
    int w = threadIdx.x >> 6;
    int wm = w >> 1, wn = w & 1;
    const float SC = 0.125f * 1.44269504f;  // scale * log2(e), folded into q
#pragma unroll
    for (int mt = 0; mt < 4; mt++) {
#pragma unroll
        for (int nt = 0; nt < 4; nt++) {
#pragma unroll
            for (int r = 0; r < 4; r++) {
                int m = blockIdx.x * 128 + wm * 64 + mt * 16 + (lane >> 4) * 4 + r;
                int n = blockIdx.y * 128 + wn * 64 + nt * 16 + (lane & 15);
                int piece = n >> 9;
                int c = n & 511;
                int h = c >> 6;
                int d = c & 63;
                int bi = m >> 12;
                int nn = m & 4095;
                int bh = bi * 8 + h;
                float av = acc[mt][nt][r];
                if (piece == 0)      qb[((size_t)(bh * SEQ + nn) << 6) + d] = f2bf(av * SC);
                else if (piece == 1) kb[((size_t)(bh * SEQ + nn) << 6) + d] = f2bf(av);
                else                 vbT[((size_t)(bh * 64 + d) << 12) + nn] = f2bf(av);
            }
        }
    }
}

// Out projection GEMM -> d_out fp32
__global__ __launch_bounds__(256) void gemm_out_kernel(const u16* __restrict__ aout,
                                                       const u16* __restrict__ wT,
                                                       float* __restrict__ out) {
    __shared__ u16 A_lds[128 * 32];
    __shared__ u16 B_lds[128 * 32];
    f32x4 acc[4][4];
    gemm_core<512>(aout, wT, blockIdx.x * 128, blockIdx.y * 128, A_lds, B_lds, acc);
    int lane = threadIdx.x & 63;
    int w = threadIdx.x >> 6;
    int wm = w >> 1, wn = w & 1;
#pragma unroll
    for (int mt = 0; mt < 4; mt++) {
#pragma unroll
        for (int nt = 0; nt < 4; nt++) {
#pragma unroll
            for (int r = 0; r < 4; r++) {
                int m = blockIdx.x * 128 + wm * 64 + mt * 16 + (lane >> 4) * 4 + r;
                int n = blockIdx.y * 128 + wn * 64 + nt * 16 + (lane & 15);
                out[(size_t)m * DIM + n] = acc[mt][nt][r];
            }
        }
    }
}

// ---------------- split-K causal flash attention (no-max softmax) ----------
// Block = (bh, qt, chunk ci); chunk covers kt in [ci*32, min(ci*32+31, qt)].
// Slot s in [0,96): qt<32 -> s=qt (ci=0); qt>=32 -> s=32+(qt-32)*2+ci.
// Partials: Onum bf16 [slot][64q][64d], l fp32 [slot][64q]; combine sums.
//
// SWAPPED-OPERAND softmax (this round): S^T = mfma(A=K, B=Q) puts each q-row
// lane-local (q = lane&15), so P is packed in-register (4 x ds_write_b64 per
// lane per tile) instead of 16 conflicted ds_write_b16. Q fragments load
// directly from global (B-operand chunk is 16B contiguous) -> no Q LDS stage.
#define ASTR 72  // K/V LDS row stride (u16): row stride 36 dw -> b128 2-way (free)
#define PSTR 72  // P scratch row stride (u16)

__global__ __launch_bounds__(256, 4) void attn_partial_kernel(const u16* __restrict__ qb,
                                                              const u16* __restrict__ kb,
                                                              const u16* __restrict__ vbT,
                                                              u16* __restrict__ part,
                                                              float* __restrict__ lpart) {
    __shared__ u16 K_lds[64 * ASTR];
    __shared__ u16 VT_lds[64 * ASTR];
    __shared__ u16 P_lds[4 * 16 * PSTR];  // per-wave P scratch (16 q-rows each)

    // XCD-aware swizzle (1536 = 8 * 192, bijective): each XCD keeps ~2 bh of
    // K/V (~2 MB) hot in its private L2. Big chunks still dispatch first
    // within each XCD's range.
    int bid = blockIdx.x;
    int bs = (bid & 7) * 192 + (bid >> 3);
    int idx = NBH * NSLOT - 1 - bs;
    int bh = idx / NSLOT;
    int s  = idx - bh * NSLOT;
    int qt, ci;
    if (s < 32) { qt = s; ci = 0; }
    else        { int t = s - 32; qt = 32 + (t >> 1); ci = t & 1; }
    int kt0 = ci * 32;
    int kt1 = min(kt0 + 31, qt);

    int tid = threadIdx.x;
    int lane = tid & 63;
    int l15 = lane & 15, g = lane >> 4;
    int w = tid >> 6;

    const u16* Kp0 = kb + (size_t)bh * SEQ * 64;
    const u16* VTp = vbT + ((size_t)bh * 64) * SEQ;

    // Q fragments (B-operand): lane holds Q[q = qt*64 + w*16 + l15][kd = g*8+j]
    const u16* Qp = qb + ((size_t)bh * SEQ + qt * 64 + w * 16 + l15) * 64;
    bf16x8 bQ0 = *(const bf16x8*)(Qp + g * 8);
    bf16x8 bQ1 = *(const bf16x8*)(Qp + 32 + g * 8);

    f32x4 Oacc[4];
    f32x4 l_acc = (f32x4){0.f, 0.f, 0.f, 0.f};
#pragma unroll
    for (int vt = 0; vt < 4; vt++) Oacc[vt] = (f32x4){0.f, 0.f, 0.f, 0.f};

    const __bf16 one_bf = (__bf16)1.0f;
    bf16x8 vones = {one_bf, one_bf, one_bf, one_bf, one_bf, one_bf, one_bf, one_bf};

    u16* Pw = P_lds + w * 16 * PSTR;

    int c0 = tid, c1 = tid + 256;
    int r0 = c0 >> 3, kc0 = (c0 & 7) * 8;
    int r1 = c1 >> 3, kc1 = (c1 & 7) * 8;

    // prefetch first k-tile
    u16x8 krA0, krA1, vrA0, vrA1;
    {
        const u16* Kp = Kp0 + (size_t)kt0 * 64 * 64;
        krA0 = *(const u16x8*)(Kp + r0 * 64 + kc0);
        krA1 = *(const u16x8*)(Kp + r1 * 64 + kc1);
        vrA0 = *(const u16x8*)(VTp + (size_t)r0 * SEQ + kt0 * 64 + kc0);
        vrA1 = *(const u16x8*)(VTp + (size_t)r1 * SEQ + kt0 * 64 + kc1);
    }

    for (int kt = kt0; kt <= kt1; kt++) {
        __syncthreads();
        *(u16x8*)(K_lds + r0 * ASTR + kc0) = krA0;
        *(u16x8*)(K_lds + r1 * ASTR + kc1) = krA1;
        *(u16x8*)(VT_lds + r0 * ASTR + kc0) = vrA0;
        *(u16x8*)(VT_lds + r1 * ASTR + kc1) = vrA1;
        // issue next tile's loads; they stay in flight across the barrier
        int ktn = (kt < kt1) ? kt + 1 : kt1;
        const u16* Kpn = Kp0 + (size_t)ktn * 64 * 64;
        u16x8 krB0 = *(const u16x8*)(Kpn + r0 * 64 + kc0);
        u16x8 krB1 = *(const u16x8*)(Kpn + r1 * 64 + kc1);
        u16x8 vrB0 = *(const u16x8*)(VTp + (size_t)r0 * SEQ + ktn * 64 + kc0);
        u16x8 vrB1 = *(const u16x8*)(VTp + (size_t)r1 * SEQ + ktn * 64 + kc1);
        __syncthreads();

        // QK^T swapped: sv[mt][r] = S[q = w*16 + l15][k = kt*64 + mt*16 + g*4 + r]
        f32x4 sv[4];
#pragma unroll
        for (int mt = 0; mt < 4; mt++) {
            bf16x8 a0 = *(const bf16x8*)(K_lds + (mt * 16 + l15) * ASTR + g * 8);
            bf16x8 a1 = *(const bf16x8*)(K_lds + (mt * 16 + l15) * ASTR + 32 + g * 8);
            f32x4 z = (f32x4){0.f, 0.f, 0.f, 0.f};
            z = mfma_bf16(a0, bQ0, z);
            z = mfma_bf16(a1, bQ1, z);
            sv[mt] = z;
        }

        // exp2 (+ causal mask on the diagonal tile), pack 4 bf16 per lane,
        // one ds_write_b64 per mt: P[q = l15][k = mt*16 + g*4 .. +3]
        if (kt != qt) {
#pragma unroll
            for (int mt = 0; mt < 4; mt++) {
                float p0 = __builtin_amdgcn_exp2f(sv[mt][0]);
                float p1 = __builtin_amdgcn_exp2f(sv[mt][1]);
                float p2 = __builtin_amdgcn_exp2f(sv[mt][2]);
                float p3 = __builtin_amdgcn_exp2f(sv[mt][3]);
                uint2 t;
                t.x = pack_bf16(p0, p1);
                t.y = pack_bf16(p2, p3);
                *(uint2*)(Pw + l15 * PSTR + mt * 16 + g * 4) = t;
            }
        } else {
            int qg = w * 16 + l15;
#pragma unroll
            for (int mt = 0; mt < 4; mt++) {
                float p[4];
#pragma unroll
                for (int r = 0; r < 4; r++) {
                    int kg = mt * 16 + g * 4 + r;
                    p[r] = (kg <= qg) ? __builtin_amdgcn_exp2f(sv[mt][r]) : 0.f;
                }
                uint2 t;
                t.x = pack_bf16(p[0], p[1]);
                t.y = pack_bf16(p[2], p[3]);
                *(uint2*)(Pw + l15 * PSTR + mt * 16 + g * 4) = t;
            }
        }

        // P back as A-operand: lane holds P[q = l15][kd = g*8+j] (two k-halves)
        bf16x8 aP0 = *(const bf16x8*)(Pw + l15 * PSTR + g * 8);
        bf16x8 aP1 = *(const bf16x8*)(Pw + l15 * PSTR + 32 + g * 8);
        l_acc = mfma_bf16(aP0, vones, l_acc);   // denominator via ones-column MFMA
        l_acc = mfma_bf16(aP1, vones, l_acc);
#pragma unroll
        for (int vt = 0; vt < 4; vt++) {
            bf16x8 bV0 = *(const bf16x8*)(VT_lds + (vt * 16 + l15) * ASTR + g * 8);
            bf16x8 bV1 = *(const bf16x8*)(VT_lds + (vt * 16 + l15) * ASTR + 32 + g * 8);
            Oacc[vt] = mfma_bf16(aP0, bV0, Oacc[vt]);
            Oacc[vt] = mfma_bf16(aP1, bV1, Oacc[vt]);
        }

        krA0 = krB0; krA1 = krB1; vrA0 = vrB0; vrA1 = vrB1;
    }

    // write partials: Onum (bf16) + l (fp32); slot == idx
    // Oacc layout: O[q = w*16 + g*4 + r][d = vt*16 + l15]
    u16* po = part + (size_t)idx * 4096;
#pragma unroll
    for (int vt = 0; vt < 4; vt++)
#pragma unroll
        for (int r = 0; r < 4; r++) {
            int q = w * 16 + g * 4 + r;
            int d = vt * 16 + l15;
            po[q * 64 + d] = f2bf(Oacc[vt][r]);
        }
    if (l15 == 0) {
#pragma unroll
        for (int r = 0; r < 4; r++)
            lpart[(size_t)idx * 64 + w * 16 + g * 4 + r] = l_acc[r];
    }
}

// combine partials -> aout bf16 [8192][512]
__global__ __launch_bounds__(256) void attn_combine_kernel(const u16* __restrict__ part,
                                                           const float* __restrict__ lpart,
                                                           u16* __restrict__ aout) {
    int bid = blockIdx.x;          // 16*64
    int bh = bid >> 6;
    int qt = bid & 63;
    int nc = 1 + (qt >> 5);
    int sb = bh * NSLOT + (qt < 32 ? qt : 32 + (qt - 32) * 2);

    int t = threadIdx.x;
    int q = t >> 2;
    int dg = (t & 3) * 16;

    float acc[16];
#pragma unroll
    for (int j = 0; j < 16; j++) acc[j] = 0.f;
    float ll = 0.f;
    for (int ci = 0; ci < nc; ci++) {
        const u16* pp = part + (size_t)(sb + ci) * 4096 + q * 64 + dg;
        u16x8 v0 = *(const u16x8*)pp;
        u16x8 v1 = *(const u16x8*)(pp + 8);
#pragma unroll
        for (int j = 0; j < 8; j++) { acc[j] += bf2f(v0[j]); acc[8 + j] += bf2f(v1[j]); }
        ll += lpart[(size_t)(sb + ci) * 64 + q];
    }
    float inv = 1.f / (ll + 1e-10f);
    int b = bh >> 3, h = bh & 7;
    size_t row = (size_t)(b * SEQ + qt * 64 + q);
    u16 o[16];
#pragma unroll
    for (int j = 0; j < 16; j++) o[j] = f2bf(acc[j] * inv);
    u16* dst = aout + row * 512 + h * 64 + dg;
    *(u16x8*)dst = *(u16x8*)o;
    *(u16x8*)(dst + 8) = *(u16x8*)(o + 8);
}

extern "C" void kernel_launch(void* const* d_in, const int* in_sizes, int n_in,
                              void* d_out, int out_size, void* d_ws, size_t ws_size,
                              hipStream_t stream) {
    const float* x    = (const float*)d_in[0];
    const float* g    = (const float*)d_in[1];
    const float* bta  = (const float*)d_in[2];
    const float* wqkv = (const float*)d_in[3];
    const float* wout = (const float*)d_in[4];
    float* out = (float*)d_out;

    char* ws = (char*)d_ws;
    size_t off = 0;
    auto alloc = [&](size_t bytes) {
        void* p = ws + off;
        off += (bytes + 255) & ~(size_t)255;
        return p;
    };
    // Footprint kept <= 46.1 MB (round-4's 54.6 MB is known-good; round-5's
    // 76 MB overran d_ws and corrupted neighboring allocations during timing).
    u16* xn    = (u16*)alloc((size_t)NTOK * DIM * 2);       // 16.78 MB; dead after gemm_qkv
    u16* wqkvT = (u16*)alloc((size_t)1536 * 1024 * 2);      //  3.15 MB
    u16* woutT = (u16*)alloc((size_t)1024 * 512 * 2);       //  1.05 MB
    u16* qb    = (u16*)alloc((size_t)NBH * SEQ * 64 * 2);   //  8.39 MB; dead after attn_partial
    u16* kb    = (u16*)alloc((size_t)NBH * SEQ * 64 * 2);   //  8.39 MB
    u16* vbT   = (u16*)alloc((size_t)NBH * SEQ * 64 * 2);   //  8.39 MB
    // Aliases (lifetimes disjoint by stream order, valid on every replay):
    u16* part  = xn;                                        // 12.58 MB into xn region
    float* lpart = (float*)(xn + (size_t)NBH * NSLOT * 4096); // +0.39 MB, still < xn's 16.78 MB
    u16* aout  = qb;                                        // combine writes after attn_partial reads qb

    ln_kernel<<<NTOK, 256, 0, stream>>>(x, g, bta, xn);
    transpose_kernel<<<dim3(1536 / 32, 1024 / 32), 256, 0, stream>>>(wqkv, wqkvT, 1024, 1536);
    transpose_kernel<<<dim3(1024 / 32, 512 / 32), 256, 0, stream>>>(wout, woutT, 512, 1024);
    gemm_qkv_kernel<<<dim3(64, 12), 256, 0, stream>>>(xn, wqkvT, qb, kb, vbT);
    attn_partial_kernel<<<NBH * NSLOT, 256, 0, stream>>>(qb, kb, vbT, part, lpart);
    attn_combine_kernel<<<NBH * 64, 256, 0, stream>>>(part, lpart, aout);
    gemm_out_kernel<<<dim3(64, 8), 256, 0, stream>>>(aout, woutT, out);
}